// Round 1
// baseline (367.802 us; speedup 1.0000x reference)
//
#include <hip/hip_runtime.h>
#include <hip/hip_bf16.h>
#include <stdint.h>

// MoE experts: E=8, T=2048, H=1024, I=2048, contiguous token groups.
// up = h@w1_e ; up_r = h@w3_e ; gated = silu(up)*up_r ; out = gated@w2_e
// bf16 MFMA compute (harness threshold is bf16 floor), fp32 accumulate.

#define NE 8
#define NT 2048
#define NH 1024
#define NI 2048

typedef __attribute__((ext_vector_type(8))) short bh8;      // 8 bf16 (4 VGPR)
typedef __attribute__((ext_vector_type(4))) float f32x4;
typedef __attribute__((ext_vector_type(2))) float f32x2;
typedef __attribute__((ext_vector_type(4))) float float4v;

static __device__ __forceinline__ unsigned short f2bf(float f) {
  __hip_bfloat16 h = __float2bfloat16(f);   // RNE
  return *reinterpret_cast<unsigned short*>(&h);
}

// ---- hiddens fp32 -> bf16 (ws) ----
__global__ __launch_bounds__(256)
void cvt_h_kernel(const float* __restrict__ x, unsigned short* __restrict__ y) {
  int i = blockIdx.x * 256 + threadIdx.x;           // one bh8 per thread
  const float4v* xv = reinterpret_cast<const float4v*>(x);
  float4v a = xv[2 * i], b = xv[2 * i + 1];
  union { bh8 v; unsigned short u[8]; } o;
  o.u[0] = f2bf(a[0]); o.u[1] = f2bf(a[1]); o.u[2] = f2bf(a[2]); o.u[3] = f2bf(a[3]);
  o.u[4] = f2bf(b[0]); o.u[5] = f2bf(b[1]); o.u[6] = f2bf(b[2]); o.u[7] = f2bf(b[3]);
  reinterpret_cast<bh8*>(y)[i] = o.v;
}

// LDS layout for all tiles: [row 128][k 32] bf16, 4 slots of 8 bf16 per row,
// slot' = slot ^ ((row>>1)&3)  -> ds_read_b128 fragment reads conflict-free.

// ---- GEMM1: fused h@w1 / h@w3 + silu-gate, writes gated bf16 ----
__global__ __launch_bounds__(256, 2)
void moe_gemm1(const unsigned short* __restrict__ hb,   // [T][H] bf16
               const float* __restrict__ w1,            // [E][H][I]
               const float* __restrict__ w3,            // [E][H][I]
               const int* __restrict__ bsz,
               unsigned short* __restrict__ gated) {    // [T][I] bf16
  const int mt = blockIdx.x, nt = blockIdx.y, e = blockIdx.z;
  int off = 0;
#pragma unroll
  for (int j = 0; j < NE; ++j) { int v = bsz[j]; off += (j < e) ? v : 0; }
  const int te = bsz[e];
  if (mt * 128 >= te) return;

  const int tid = threadIdx.x;
  const int lw = tid & 63, wv = tid >> 6;
  const int wr = wv >> 1, wc = wv & 1;

  __shared__ __align__(16) unsigned short As[128 * 32];
  __shared__ __align__(16) unsigned short B1s[128 * 32];
  __shared__ __align__(16) unsigned short B3s[128 * 32];

  const int row0 = off + mt * 128;
  const int col0 = nt * 128;

  // A staging: global_load_lds, lane l of chunk c covers row c*16+(l>>2),
  // LDS slot l&3; pre-swizzled global source slot = (l&3)^((l>>3)&3).
  const int c0 = wv * 2, c1 = wv * 2 + 1;
  const int gsl = ((lw & 3) ^ ((lw >> 3) & 3)) * 8;
  int gr0 = row0 + c0 * 16 + (lw >> 2); if (gr0 > NT - 1) gr0 = NT - 1;
  int gr1 = row0 + c1 * 16 + (lw >> 2); if (gr1 > NT - 1) gr1 = NT - 1;
  const unsigned short* ag0 = hb + (size_t)gr0 * NH + gsl;
  const unsigned short* ag1 = hb + (size_t)gr1 * NH + gsl;

  // B staging: thread t covers n2=(t&63)*2 (+1), k-slot kh=t>>6 (8 k's),
  // fp32 loads (stride NI, coalesced across lanes), cvt, b128 write transposed.
  const int n2 = (tid & 63) * 2;
  const int kh = tid >> 6;
  const int swsl = (kh ^ ((n2 >> 1) & 3)) * 8;
  const float* w1p = w1 + (size_t)e * NH * NI + (size_t)(kh * 8) * NI + (col0 + n2);
  const float* w3p = w3 + (size_t)e * NH * NI + (size_t)(kh * 8) * NI + (col0 + n2);

  // fragment reads: lane lw reads row base+(lw&15), logical k-slot lw>>4
  const int fsl = (((lw >> 4) ^ ((lw >> 1) & 3))) * 8;
  const int arow = wr * 64 + (lw & 15);
  const int brow = wc * 64 + (lw & 15);

  f32x4 acc1[4][4] = {};
  f32x4 acc3[4][4] = {};

  for (int k0 = 0; k0 < NH; k0 += 32) {
    __builtin_amdgcn_global_load_lds(
        (const __attribute__((address_space(1))) void*)(ag0 + k0),
        (__attribute__((address_space(3))) void*)(As + c0 * 512), 16, 0, 0);
    __builtin_amdgcn_global_load_lds(
        (const __attribute__((address_space(1))) void*)(ag1 + k0),
        (__attribute__((address_space(3))) void*)(As + c1 * 512), 16, 0, 0);
    {
      const float* p1 = w1p + (size_t)k0 * NI;
      const float* p3 = w3p + (size_t)k0 * NI;
      union { bh8 v; unsigned short u[8]; } q0, q1, r0, r1;
#pragma unroll
      for (int j = 0; j < 8; ++j) {
        f32x2 u = *(const f32x2*)(p1 + (size_t)j * NI);
        q0.u[j] = f2bf(u[0]); q1.u[j] = f2bf(u[1]);
      }
#pragma unroll
      for (int j = 0; j < 8; ++j) {
        f32x2 u = *(const f32x2*)(p3 + (size_t)j * NI);
        r0.u[j] = f2bf(u[0]); r1.u[j] = f2bf(u[1]);
      }
      *(bh8*)(B1s + n2 * 32 + swsl) = q0.v;
      *(bh8*)(B1s + (n2 + 1) * 32 + swsl) = q1.v;
      *(bh8*)(B3s + n2 * 32 + swsl) = r0.v;
      *(bh8*)(B3s + (n2 + 1) * 32 + swsl) = r1.v;
    }
    __syncthreads();

    bh8 af[4];
#pragma unroll
    for (int m = 0; m < 4; ++m)
      af[m] = *(const bh8*)(As + (arow + m * 16) * 32 + fsl);
#pragma unroll
    for (int n = 0; n < 4; ++n) {
      bh8 b1f = *(const bh8*)(B1s + (brow + n * 16) * 32 + fsl);
      bh8 b3f = *(const bh8*)(B3s + (brow + n * 16) * 32 + fsl);
#pragma unroll
      for (int m = 0; m < 4; ++m) {
        acc1[m][n] = __builtin_amdgcn_mfma_f32_16x16x32_bf16(af[m], b1f, acc1[m][n], 0, 0, 0);
        acc3[m][n] = __builtin_amdgcn_mfma_f32_16x16x32_bf16(af[m], b3f, acc3[m][n], 0, 0, 0);
      }
    }
    __syncthreads();
  }

  // epilogue: silu(acc1)*acc3 -> gated (bf16), masked by ragged bound
  const int rb = wr * 64 + ((lw >> 4) << 2);
  const int cb = col0 + wc * 64 + (lw & 15);
#pragma unroll
  for (int m = 0; m < 4; ++m) {
#pragma unroll
    for (int r = 0; r < 4; ++r) {
      int trow = mt * 128 + rb + m * 16 + r;
      if (trow < te) {
        size_t base = (size_t)(off + trow) * NI + cb;
#pragma unroll
        for (int n = 0; n < 4; ++n) {
          float u = acc1[m][n][r];
          float g = acc3[m][n][r];
          float s = u / (1.f + __expf(-u));
          gated[base + n * 16] = f2bf(s * g);
        }
      }
    }
  }
}

// ---- GEMM2: gated @ w2 -> out fp32 ----
__global__ __launch_bounds__(256, 2)
void moe_gemm2(const unsigned short* __restrict__ gated,  // [T][I] bf16
               const float* __restrict__ w2,              // [E][I][H]
               const int* __restrict__ bsz,
               float* __restrict__ out) {                 // [T][H] fp32
  const int mt = blockIdx.x, nt = blockIdx.y, e = blockIdx.z;
  int off = 0;
#pragma unroll
  for (int j = 0; j < NE; ++j) { int v = bsz[j]; off += (j < e) ? v : 0; }
  const int te = bsz[e];
  if (mt * 128 >= te) return;

  const int tid = threadIdx.x;
  const int lw = tid & 63, wv = tid >> 6;
  const int wr = wv >> 1, wc = wv & 1;

  __shared__ __align__(16) unsigned short As[128 * 32];
  __shared__ __align__(16) unsigned short Bs[128 * 32];

  const int row0 = off + mt * 128;
  const int col0 = nt * 128;

  const int c0 = wv * 2, c1 = wv * 2 + 1;
  const int gsl = ((lw & 3) ^ ((lw >> 3) & 3)) * 8;
  int gr0 = row0 + c0 * 16 + (lw >> 2); if (gr0 > NT - 1) gr0 = NT - 1;
  int gr1 = row0 + c1 * 16 + (lw >> 2); if (gr1 > NT - 1) gr1 = NT - 1;
  const unsigned short* ag0 = gated + (size_t)gr0 * NI + gsl;
  const unsigned short* ag1 = gated + (size_t)gr1 * NI + gsl;

  const int n2 = (tid & 63) * 2;
  const int kh = tid >> 6;
  const int swsl = (kh ^ ((n2 >> 1) & 3)) * 8;
  const float* w2p = w2 + (size_t)e * NI * NH + (size_t)(kh * 8) * NH + (col0 + n2);

  const int fsl = (((lw >> 4) ^ ((lw >> 1) & 3))) * 8;
  const int arow = wr * 64 + (lw & 15);
  const int brow = wc * 64 + (lw & 15);

  f32x4 acc[4][4] = {};

  for (int k0 = 0; k0 < NI; k0 += 32) {
    __builtin_amdgcn_global_load_lds(
        (const __attribute__((address_space(1))) void*)(ag0 + k0),
        (__attribute__((address_space(3))) void*)(As + c0 * 512), 16, 0, 0);
    __builtin_amdgcn_global_load_lds(
        (const __attribute__((address_space(1))) void*)(ag1 + k0),
        (__attribute__((address_space(3))) void*)(As + c1 * 512), 16, 0, 0);
    {
      const float* p = w2p + (size_t)k0 * NH;
      union { bh8 v; unsigned short u[8]; } q0, q1;
#pragma unroll
      for (int j = 0; j < 8; ++j) {
        f32x2 u = *(const f32x2*)(p + (size_t)j * NH);
        q0.u[j] = f2bf(u[0]); q1.u[j] = f2bf(u[1]);
      }
      *(bh8*)(Bs + n2 * 32 + swsl) = q0.v;
      *(bh8*)(Bs + (n2 + 1) * 32 + swsl) = q1.v;
    }
    __syncthreads();

    bh8 af[4];
#pragma unroll
    for (int m = 0; m < 4; ++m)
      af[m] = *(const bh8*)(As + (arow + m * 16) * 32 + fsl);
#pragma unroll
    for (int n = 0; n < 4; ++n) {
      bh8 bf = *(const bh8*)(Bs + (brow + n * 16) * 32 + fsl);
#pragma unroll
      for (int m = 0; m < 4; ++m)
        acc[m][n] = __builtin_amdgcn_mfma_f32_16x16x32_bf16(af[m], bf, acc[m][n], 0, 0, 0);
    }
    __syncthreads();
  }

  const int rb = wr * 64 + ((lw >> 4) << 2);
  const int cb = col0 + wc * 64 + (lw & 15);
#pragma unroll
  for (int m = 0; m < 4; ++m) {
#pragma unroll
    for (int r = 0; r < 4; ++r) {
      int trow = mt * 128 + rb + m * 16 + r;
      if (trow < te) {
        size_t base = (size_t)(off + trow) * NH + cb;
#pragma unroll
        for (int n = 0; n < 4; ++n)
          out[base + n * 16] = acc[m][n][r];
      }
    }
  }
}

extern "C" void kernel_launch(void* const* d_in, const int* in_sizes, int n_in,
                              void* d_out, int out_size, void* d_ws, size_t ws_size,
                              hipStream_t stream) {
  const float* hiddens = (const float*)d_in[0];
  const float* w1 = (const float*)d_in[1];
  const float* w2 = (const float*)d_in[2];
  const float* w3 = (const float*)d_in[3];
  const int* bsz = (const int*)d_in[4];
  float* out = (float*)d_out;

  // ws: [0, 4MB) hiddens bf16 ; [4MB, 12MB) gated bf16
  unsigned short* hb = (unsigned short*)d_ws;
  unsigned short* gated = hb + (size_t)NT * NH;

  cvt_h_kernel<<<dim3(NT * NH / 8 / 256), dim3(256), 0, stream>>>(hiddens, hb);
  moe_gemm1<<<dim3(16, 16, NE), dim3(256), 0, stream>>>(hb, w1, w3, bsz, gated);
  moe_gemm2<<<dim3(16, 8, NE), dim3(256), 0, stream>>>(gated, w2, bsz, out);
}

// Round 2
// 178.972 us; speedup vs baseline: 2.0551x; 2.0551x over previous
//
#include <hip/hip_runtime.h>
#include <hip/hip_bf16.h>
#include <stdint.h>

// MoE experts: E=8, T=2048, H=1024, I=2048, contiguous token groups.
// up = h@w1_e ; up_r = h@w3_e ; gated = silu(up)*up_r ; out = gated@w2_e
// bf16 MFMA compute, fp32 accumulate. Weights converted fp32->bf16 on the fly.
//
// Round-2: fix XCD clustering (bijective chunk swizzle on a 1-D grid),
// 64x128 tiles for 2x more working blocks, double-buffered LDS with
// T14 split-stage (issue loads early / cvt+ds_write late) to hide HBM latency.

#define NE 8
#define NT 2048
#define NH 1024
#define NI 2048

typedef __attribute__((ext_vector_type(8))) short bh8;      // 8 bf16 (4 VGPR)
typedef __attribute__((ext_vector_type(4))) float f32x4;
typedef __attribute__((ext_vector_type(2))) float f32x2;
typedef __attribute__((ext_vector_type(4))) float float4v;

static __device__ __forceinline__ unsigned short f2bf(float f) {
  __hip_bfloat16 h = __float2bfloat16(f);   // RNE
  return *reinterpret_cast<unsigned short*>(&h);
}

// ---- hiddens fp32 -> bf16 (ws) ----
__global__ __launch_bounds__(256)
void cvt_h_kernel(const float* __restrict__ x, unsigned short* __restrict__ y) {
  int i = blockIdx.x * 256 + threadIdx.x;           // one bh8 per thread
  const float4v* xv = reinterpret_cast<const float4v*>(x);
  float4v a = xv[2 * i], b = xv[2 * i + 1];
  union { bh8 v; unsigned short u[8]; } o;
  o.u[0] = f2bf(a[0]); o.u[1] = f2bf(a[1]); o.u[2] = f2bf(a[2]); o.u[3] = f2bf(a[3]);
  o.u[4] = f2bf(b[0]); o.u[5] = f2bf(b[1]); o.u[6] = f2bf(b[2]); o.u[7] = f2bf(b[3]);
  reinterpret_cast<bh8*>(y)[i] = o.v;
}

// ============ GEMM1: fused h@w1 / h@w3 + silu-gate -> gated bf16 ============
// BM=64 BN=128 BK=32, 4 waves (2x2), double-buffered LDS, grid 1-D swizzled.
__global__ __launch_bounds__(256, 2)
void moe_gemm1(const unsigned short* __restrict__ hb,   // [T][H] bf16
               const float* __restrict__ w1,            // [E][H][I]
               const float* __restrict__ w3,            // [E][H][I]
               const int* __restrict__ bsz,
               unsigned short* __restrict__ gated) {    // [T][I] bf16
  const int NWG = 32 * 16 * NE;                 // mt(32) x nt(16) x e(8) = 4096
  const int phys = blockIdx.x;
  const int wg = (phys & 7) * (NWG >> 3) + (phys >> 3);   // XCD-chunked, bijective
  const int mt = wg & 31;                       // fastest: same (nt,e) share B-panel
  const int nt = (wg >> 5) & 15;
  const int e = wg >> 9;

  int off = 0;
#pragma unroll
  for (int j = 0; j < NE; ++j) { int v = bsz[j]; off += (j < e) ? v : 0; }
  const int te = bsz[e];
  if (mt * 64 >= te) return;

  const int tid = threadIdx.x;
  const int lw = tid & 63, wv = tid >> 6;
  const int wr = wv >> 1, wc = wv & 1;

  __shared__ __align__(16) unsigned short As[2][64 * 32];     // 2 x 4KB
  __shared__ __align__(16) unsigned short B1s[2][128 * 32];   // 2 x 8KB
  __shared__ __align__(16) unsigned short B3s[2][128 * 32];   // 2 x 8KB

  const int row0 = off + mt * 64;
  const int col0 = nt * 128;

  // A staging: 4 chunks (1/wave) of 16 rows; lane l: row wv*16+(l>>2), slot l&3.
  // LDS dest linear; global source slot pre-swizzled: (l&3)^((l>>3)&3).
  int gr = row0 + wv * 16 + (lw >> 2); if (gr > NT - 1) gr = NT - 1;
  const int gsl = ((lw & 3) ^ ((lw >> 3) & 3)) * 8;
  const unsigned short* agA = hb + (size_t)gr * NH + gsl;

  // B staging: thread covers n2,(n2+1) cols, k-slot kh (8 k's), fp32 loads.
  const int n2 = (tid & 63) * 2;
  const int kh = tid >> 6;
  const int swsl = (kh ^ ((n2 >> 1) & 3)) * 8;
  const float* w1p = w1 + (size_t)e * NH * NI + (size_t)(kh * 8) * NI + (col0 + n2);
  const float* w3p = w3 + (size_t)e * NH * NI + (size_t)(kh * 8) * NI + (col0 + n2);

  // fragment reads
  const int fsl = ((lw >> 4) ^ ((lw >> 1) & 3)) * 8;
  const int arow = wr * 32 + (lw & 15);
  const int brow = wc * 64 + (lw & 15);

  f32x4 acc1[2][4] = {};
  f32x4 acc3[2][4] = {};
  f32x2 rb1[8], rb3[8];

  auto issueA = [&](int k0, int b) {
    __builtin_amdgcn_global_load_lds(
        (const __attribute__((address_space(1))) void*)(agA + k0),
        (__attribute__((address_space(3))) void*)(&As[b][0] + wv * 512), 16, 0, 0);
  };
  auto loadB = [&](int k0) {
    const float* p1 = w1p + (size_t)k0 * NI;
    const float* p3 = w3p + (size_t)k0 * NI;
#pragma unroll
    for (int j = 0; j < 8; ++j) rb1[j] = *(const f32x2*)(p1 + (size_t)j * NI);
#pragma unroll
    for (int j = 0; j < 8; ++j) rb3[j] = *(const f32x2*)(p3 + (size_t)j * NI);
  };
  auto writeB = [&](int b) {
    union { bh8 v; unsigned short u[8]; } q0, q1, r0, r1;
#pragma unroll
    for (int j = 0; j < 8; ++j) { q0.u[j] = f2bf(rb1[j][0]); q1.u[j] = f2bf(rb1[j][1]); }
#pragma unroll
    for (int j = 0; j < 8; ++j) { r0.u[j] = f2bf(rb3[j][0]); r1.u[j] = f2bf(rb3[j][1]); }
    *(bh8*)(&B1s[b][0] + n2 * 32 + swsl) = q0.v;
    *(bh8*)(&B1s[b][0] + (n2 + 1) * 32 + swsl) = q1.v;
    *(bh8*)(&B3s[b][0] + n2 * 32 + swsl) = r0.v;
    *(bh8*)(&B3s[b][0] + (n2 + 1) * 32 + swsl) = r1.v;
  };

  // prologue: stage tile 0 into buf 0
  issueA(0, 0);
  loadB(0);
  writeB(0);
  __syncthreads();

  for (int t = 0; t < 32; ++t) {
    const int cb = t & 1, nb = cb ^ 1;
    if (t + 1 < 32) {               // issue next-tile loads BEFORE compute
      issueA((t + 1) * 32, nb);
      loadB((t + 1) * 32);
    }
    bh8 af[2];
#pragma unroll
    for (int m = 0; m < 2; ++m)
      af[m] = *(const bh8*)(&As[cb][0] + (arow + m * 16) * 32 + fsl);
#pragma unroll
    for (int n = 0; n < 4; ++n) {
      bh8 b1f = *(const bh8*)(&B1s[cb][0] + (brow + n * 16) * 32 + fsl);
      bh8 b3f = *(const bh8*)(&B3s[cb][0] + (brow + n * 16) * 32 + fsl);
#pragma unroll
      for (int m = 0; m < 2; ++m) {
        acc1[m][n] = __builtin_amdgcn_mfma_f32_16x16x32_bf16(af[m], b1f, acc1[m][n], 0, 0, 0);
        acc3[m][n] = __builtin_amdgcn_mfma_f32_16x16x32_bf16(af[m], b3f, acc3[m][n], 0, 0, 0);
      }
    }
    if (t + 1 < 32) writeB(nb);     // cvt + ds_write AFTER compute (T14)
    __syncthreads();
  }

  // epilogue: silu(acc1)*acc3 -> gated bf16, masked by ragged bound
  const int rb = wr * 32 + ((lw >> 4) << 2);
  const int cbs = col0 + wc * 64 + (lw & 15);
#pragma unroll
  for (int m = 0; m < 2; ++m) {
#pragma unroll
    for (int r = 0; r < 4; ++r) {
      int trow = mt * 64 + rb + m * 16 + r;
      if (trow < te) {
        size_t base = (size_t)(off + trow) * NI + cbs;
#pragma unroll
        for (int n = 0; n < 4; ++n) {
          float u = acc1[m][n][r];
          float g = acc3[m][n][r];
          gated[base + n * 16] = f2bf((u / (1.f + __expf(-u))) * g);
        }
      }
    }
  }
}

// ============ GEMM2: gated @ w2 -> out fp32 ============
// BM=64 BN=128 BK=64, 4 waves (2x2), double-buffered LDS.
__global__ __launch_bounds__(256, 2)
void moe_gemm2(const unsigned short* __restrict__ gated,  // [T][I] bf16
               const float* __restrict__ w2,              // [E][I][H]
               const int* __restrict__ bsz,
               float* __restrict__ out) {                 // [T][H] fp32
  const int NWG = 32 * 8 * NE;                  // mt(32) x nt(8) x e(8) = 2048
  const int phys = blockIdx.x;
  const int wg = (phys & 7) * (NWG >> 3) + (phys >> 3);
  const int mt = wg & 31;
  const int nt = (wg >> 5) & 7;
  const int e = wg >> 8;

  int off = 0;
#pragma unroll
  for (int j = 0; j < NE; ++j) { int v = bsz[j]; off += (j < e) ? v : 0; }
  const int te = bsz[e];
  if (mt * 64 >= te) return;

  const int tid = threadIdx.x;
  const int lw = tid & 63, wv = tid >> 6;
  const int wr = wv >> 1, wc = wv & 1;

  __shared__ __align__(16) unsigned short As[2][64 * 64];    // 2 x 8KB
  __shared__ __align__(16) unsigned short Bs[2][128 * 64];   // 2 x 16KB

  const int row0 = off + mt * 64;
  const int col0 = nt * 128;

  // A staging: 8 chunks of 8 rows (2/wave); lane l: row c*8+(l>>3), slot l&7.
  // swizzle: LDS[row][s] = global[row][s ^ (row&7)]
  int gr0 = row0 + (wv * 2) * 8 + (lw >> 3); if (gr0 > NT - 1) gr0 = NT - 1;
  int gr1 = row0 + (wv * 2 + 1) * 8 + (lw >> 3); if (gr1 > NT - 1) gr1 = NT - 1;
  const int gslA = ((lw & 7) ^ (lw >> 3)) * 8;
  const unsigned short* agA0 = gated + (size_t)gr0 * NI + gslA;
  const unsigned short* agA1 = gated + (size_t)gr1 * NI + gslA;

  // B staging: thread covers n2,(n2+1), k rows kh*16+j (j=0..15), stride NH.
  const int n2 = (tid & 63) * 2;
  const int kh = tid >> 6;
  const float* w2p = w2 + (size_t)e * NI * NH + (size_t)(kh * 16) * NH + (col0 + n2);

  const int r7 = lw & 7;
  const int s4 = lw >> 4;          // 0..3
  const int arow = wr * 32 + (lw & 15);
  const int brow = wc * 64 + (lw & 15);

  f32x4 acc[2][4] = {};
  f32x2 rb[16];

  auto issueA = [&](int k0, int b) {
    __builtin_amdgcn_global_load_lds(
        (const __attribute__((address_space(1))) void*)(agA0 + k0),
        (__attribute__((address_space(3))) void*)(&As[b][0] + wv * 1024), 16, 0, 0);
    __builtin_amdgcn_global_load_lds(
        (const __attribute__((address_space(1))) void*)(agA1 + k0),
        (__attribute__((address_space(3))) void*)(&As[b][0] + wv * 1024 + 512), 16, 0, 0);
  };
  auto loadB = [&](int k0) {
    const float* p = w2p + (size_t)k0 * NH;
#pragma unroll
    for (int j = 0; j < 16; ++j) rb[j] = *(const f32x2*)(p + (size_t)j * NH);
  };
  auto writeB = [&](int b) {
    union { bh8 v; unsigned short u[8]; } qa, qb, qc, qd;
#pragma unroll
    for (int j = 0; j < 8; ++j) { qa.u[j] = f2bf(rb[j][0]); qc.u[j] = f2bf(rb[j][1]); }
#pragma unroll
    for (int j = 0; j < 8; ++j) { qb.u[j] = f2bf(rb[j + 8][0]); qd.u[j] = f2bf(rb[j + 8][1]); }
    const int e0 = n2 & 7, e1 = (n2 + 1) & 7;
    *(bh8*)(&Bs[b][0] + n2 * 64 + ((kh * 2) ^ e0) * 8) = qa.v;
    *(bh8*)(&Bs[b][0] + n2 * 64 + ((kh * 2 + 1) ^ e0) * 8) = qb.v;
    *(bh8*)(&Bs[b][0] + (n2 + 1) * 64 + ((kh * 2) ^ e1) * 8) = qc.v;
    *(bh8*)(&Bs[b][0] + (n2 + 1) * 64 + ((kh * 2 + 1) ^ e1) * 8) = qd.v;
  };

  issueA(0, 0);
  loadB(0);
  writeB(0);
  __syncthreads();

  for (int t = 0; t < 32; ++t) {
    const int cb = t & 1, nb = cb ^ 1;
    if (t + 1 < 32) {
      issueA((t + 1) * 64, nb);
      loadB((t + 1) * 64);
    }
    bh8 af[2][2];
#pragma unroll
    for (int kk = 0; kk < 2; ++kk)
#pragma unroll
      for (int m = 0; m < 2; ++m)
        af[kk][m] = *(const bh8*)(&As[cb][0] + (arow + m * 16) * 64 +
                                  (((kk * 4 + s4) ^ r7) * 8));
#pragma unroll
    for (int n = 0; n < 4; ++n) {
#pragma unroll
      for (int kk = 0; kk < 2; ++kk) {
        bh8 bf = *(const bh8*)(&Bs[cb][0] + (brow + n * 16) * 64 +
                               (((kk * 4 + s4) ^ r7) * 8));
#pragma unroll
        for (int m = 0; m < 2; ++m)
          acc[m][n] = __builtin_amdgcn_mfma_f32_16x16x32_bf16(af[kk][m], bf, acc[m][n], 0, 0, 0);
      }
    }
    if (t + 1 < 32) writeB(nb);
    __syncthreads();
  }

  const int rb2 = wr * 32 + ((lw >> 4) << 2);
  const int cbs = col0 + wc * 64 + (lw & 15);
#pragma unroll
  for (int m = 0; m < 2; ++m) {
#pragma unroll
    for (int r = 0; r < 4; ++r) {
      int trow = mt * 64 + rb2 + m * 16 + r;
      if (trow < te) {
        size_t base = (size_t)(off + trow) * NH + cbs;
#pragma unroll
        for (int n = 0; n < 4; ++n)
          out[base + n * 16] = acc[m][n][r];
      }
    }
  }
}

extern "C" void kernel_launch(void* const* d_in, const int* in_sizes, int n_in,
                              void* d_out, int out_size, void* d_ws, size_t ws_size,
                              hipStream_t stream) {
  const float* hiddens = (const float*)d_in[0];
  const float* w1 = (const float*)d_in[1];
  const float* w2 = (const float*)d_in[2];
  const float* w3 = (const float*)d_in[3];
  const int* bsz = (const int*)d_in[4];
  float* out = (float*)d_out;

  // ws: [0, 4MB) hiddens bf16 ; [4MB, 12MB) gated bf16
  unsigned short* hb = (unsigned short*)d_ws;
  unsigned short* gated = hb + (size_t)NT * NH;

  cvt_h_kernel<<<dim3(NT * NH / 8 / 256), dim3(256), 0, stream>>>(hiddens, hb);
  moe_gemm1<<<dim3(32 * 16 * NE), dim3(256), 0, stream>>>(hb, w1, w3, bsz, gated);
  moe_gemm2<<<dim3(32 * 8 * NE), dim3(256), 0, stream>>>(gated, w2, bsz, out);
}